// Round 1
// baseline (103901.440 us; speedup 1.0000x reference)
//
#include <hip/hip_runtime.h>
#include <hip/hip_bf16.h>

// ---------------- dims ----------------
#define T_IN_D 300
#define A_IN_D 74
#define V_IN_D 36
#define X_IN_D 410
#define T_HD 256
#define A_HD 64
#define V_HD 64
#define MEM_D 256
#define ATTN_D 768
#define T_STEPS_D 128
#define NBATCH 512

// ws layout (bf16 element offsets). Weights stored TRANSPOSED: WT[k][n] = W[n][k].
#define OFF_TWI   0L         // [556][1024]  (rows 0-299 t_Wi^T, 300-555 t_Wh^T)
#define OFF_TWH   307200L
#define OFF_AWI   569344L    // [138][256]
#define OFF_AWH   588288L
#define OFF_VWI   604672L    // [100][256]
#define OFF_VWH   613888L
#define OFF_A1W1  630272L    // [768][512]
#define OFF_A1W2  1023488L   // [512][768]
#define OFF_A2W1  1416704L   // [768][512]
#define OFF_A2W2  1809920L   // [512][256]
#define OFF_GW1   1940992L   // [1024][1024] cols 0-511 g1_w1^T, 512-1023 g2_w1^T
#define OFF_GW2   2989568L   // [1024][512]  block-diagonal: (k<512,n<256)=g1_w2^T, (k>=512,n>=256)=g2_w2^T
#define OFF_OW1   3513856L   // [640][512]
#define BF_TOTAL  3841536L   // bf16 elements; fp32 packed biases follow (gb1[1024], gb2[512])

__device__ __forceinline__ float bf2f(unsigned short h) {
    union { unsigned u; float f; } v; v.u = ((unsigned)h) << 16; return v.f;
}
__device__ __forceinline__ float sigm(float x) { return 1.f / (1.f + __expf(-x)); }
__device__ __forceinline__ float tanh_fast(float x) {
    float e = __expf(2.f * x);
    return 1.f - 2.f / (e + 1.f);
}

struct Part { const float* act; int K; int stride; };

// out[r][n0..n0+CB) for r=0,1.  WT: bf16 [sum(K)][N] row-major.  256 threads, N == 256*CB.
// MODE: 0 none, 1 relu, 2 tanh
template<int CB, int MODE>
__device__ __forceinline__ void gemmT(const Part* parts, int np,
                                      const unsigned short* __restrict__ WT, int N,
                                      const float* __restrict__ bias,
                                      float* out, int outStride)
{
    const int tid = threadIdx.x;
    const int n0 = tid * CB;
    float acc0[CB], acc1[CB];
#pragma unroll
    for (int c = 0; c < CB; ++c) { float b = bias[n0 + c]; acc0[c] = b; acc1[c] = b; }
    const unsigned short* w = WT + n0;
    for (int p = 0; p < np; ++p) {
        const float* a0 = parts[p].act;
        const float* a1 = a0 + parts[p].stride;
        const int K = parts[p].K;
        int k = 0;
        for (; k + 4 <= K; k += 4) {
            const float4 x0 = *(const float4*)(a0 + k);
            const float4 x1 = *(const float4*)(a1 + k);
            float xa0[4] = {x0.x, x0.y, x0.z, x0.w};
            float xa1[4] = {x1.x, x1.y, x1.z, x1.w};
#pragma unroll
            for (int kk = 0; kk < 4; ++kk) {
                float wv[CB];
                if constexpr (CB == 4) {
                    unsigned long long u = *(const unsigned long long*)w;
                    wv[0] = bf2f((unsigned short)u);
                    wv[1] = bf2f((unsigned short)(u >> 16));
                    wv[2] = bf2f((unsigned short)(u >> 32));
                    wv[3] = bf2f((unsigned short)(u >> 48));
                } else if constexpr (CB == 2) {
                    unsigned u = *(const unsigned*)w;
                    wv[0] = bf2f((unsigned short)u);
                    wv[1] = bf2f((unsigned short)(u >> 16));
                } else {
#pragma unroll
                    for (int c = 0; c < CB; ++c) wv[c] = bf2f(w[c]);
                }
#pragma unroll
                for (int c = 0; c < CB; ++c) {
                    acc0[c] += xa0[kk] * wv[c];
                    acc1[c] += xa1[kk] * wv[c];
                }
                w += N;
            }
        }
        for (; k < K; ++k) {  // tail (only K=74 path)
            float v0 = a0[k], v1 = a1[k];
            float wv[CB];
#pragma unroll
            for (int c = 0; c < CB; ++c) wv[c] = bf2f(w[c]);
#pragma unroll
            for (int c = 0; c < CB; ++c) {
                acc0[c] += v0 * wv[c];
                acc1[c] += v1 * wv[c];
            }
            w += N;
        }
    }
#pragma unroll
    for (int c = 0; c < CB; ++c) {
        float v0 = acc0[c], v1 = acc1[c];
        if constexpr (MODE == 1) { v0 = fmaxf(v0, 0.f); v1 = fmaxf(v1, 0.f); }
        if constexpr (MODE == 2) { v0 = tanh_fast(v0); v1 = tanh_fast(v1); }
        out[n0 + c] = v0;
        out[outStride + n0 + c] = v1;
    }
}

// -------- prologue kernels --------
__global__ void k_transpose(const float* __restrict__ src, unsigned short* __restrict__ dst,
                            int N, int K, int stride, int rowOff, int colOff)
{
    long i = (long)blockIdx.x * 256 + threadIdx.x;
    if (i >= (long)N * K) return;
    int n = (int)(i / K);
    int k = (int)(i - (long)n * K);
    __hip_bfloat16 b = __float2bfloat16(src[i]);
    dst[(long)(k + rowOff) * stride + colOff + n] = *reinterpret_cast<unsigned short*>(&b);
}

__global__ void k_packbias(const float* __restrict__ g1b1, const float* __restrict__ g2b1,
                           const float* __restrict__ g1b2, const float* __restrict__ g2b2,
                           float* __restrict__ gb)
{
    int i = blockIdx.x * 256 + threadIdx.x;
    if (i < 512) gb[i] = g1b1[i];
    else if (i < 1024) gb[i] = g2b1[i - 512];
    else if (i < 1280) gb[i] = g1b2[i - 1024];
    else if (i < 1536) gb[i] = g2b2[i - 1280];
}

// -------- main persistent kernel: one WG handles 2 batch rows for all 128 steps --------
__global__ __launch_bounds__(256)
void fused_rnn(const float* __restrict__ x_p,
               const float* __restrict__ c_t0, const float* __restrict__ c_a0,
               const float* __restrict__ c_v0, const float* __restrict__ mem0,
               const float* __restrict__ t_b, const float* __restrict__ a_b,
               const float* __restrict__ v_b,
               const float* __restrict__ a1b1, const float* __restrict__ a1b2,
               const float* __restrict__ a2b1, const float* __restrict__ a2b2,
               const float* __restrict__ ob1, const float* __restrict__ ow2,
               const float* __restrict__ ob2,
               const unsigned short* __restrict__ wsb, const float* __restrict__ wsf,
               float* __restrict__ out)
{
    const int tid = threadIdx.x;
    const int row0 = blockIdx.x * 2;

    __shared__ alignas(16) float sX[2][424];     // xt @0 (300), xa @304 (74), xv @384 (36)
    __shared__ alignas(16) float sZ[2][1024];    // z_t / scores / hidg
    __shared__ alignas(16) float sZa[2][256];
    __shared__ alignas(16) float sZv[2][256];
    __shared__ alignas(16) float sTc[2][256];
    __shared__ alignas(16) float sAc[2][64];
    __shared__ alignas(16) float sVc[2][64];
    __shared__ alignas(16) float sTh[2][256];
    __shared__ alignas(16) float sAh[2][64];
    __shared__ alignas(16) float sVh[2][64];
    __shared__ alignas(16) float sM[2][256];
    __shared__ alignas(16) float sCs[2][768];    // c_star, then attended (in place)
    __shared__ alignas(16) float sHid[2][512];   // relu hiddens / gammas
    __shared__ alignas(16) float sChat[2][256];
    __shared__ alignas(16) float sR[2][256];
    __shared__ float sRed[2];

    // init states
    for (int i = tid; i < 2 * 256; i += 256) {
        int r = i >> 8, j = i & 255;
        sTc[r][j] = c_t0[(row0 + r) * T_HD + j];
        sTh[r][j] = 0.f;
        sM[r][j] = mem0[(row0 + r) * MEM_D + j];
    }
    for (int i = tid; i < 2 * 64; i += 256) {
        int r = i >> 6, j = i & 63;
        sAc[r][j] = c_a0[(row0 + r) * A_HD + j]; sAh[r][j] = 0.f;
        sVc[r][j] = c_v0[(row0 + r) * V_HD + j]; sVh[r][j] = 0.f;
    }
    __syncthreads();

    for (int t = 0; t < T_STEPS_D; ++t) {
        // load x rows (padded layout) + copy pre_c into c_star[0:384]
        const float* xb = x_p + ((long)t * NBATCH + row0) * X_IN_D;
        for (int i = tid; i < 2 * X_IN_D; i += 256) {
            int r = i / X_IN_D, c = i - r * X_IN_D;
            int lc = (c < 300) ? c : ((c < 374) ? c + 4 : c + 10);
            sX[r][lc] = xb[r * X_IN_D + c];
        }
        for (int i = tid; i < 2 * 384; i += 256) {
            int r = i / 384, c = i - r * 384;
            float v = (c < 256) ? sTc[r][c] : ((c < 320) ? sAc[r][c - 256] : sVc[r][c - 320]);
            sCs[r][c] = v;
        }
        __syncthreads();

        // LSTM pre-activations
        { Part p[2] = {{&sX[0][0], T_IN_D, 424}, {&sTh[0][0], T_HD, 256}};
          gemmT<4, 0>(p, 2, wsb + OFF_TWI, 1024, t_b, &sZ[0][0], 1024); }
        { Part p[2] = {{&sX[0][304], A_IN_D, 424}, {&sAh[0][0], A_HD, 64}};
          gemmT<1, 0>(p, 2, wsb + OFF_AWI, 256, a_b, &sZa[0][0], 256); }
        { Part p[2] = {{&sX[0][384], V_IN_D, 424}, {&sVh[0][0], V_HD, 64}};
          gemmT<1, 0>(p, 2, wsb + OFF_VWI, 256, v_b, &sZv[0][0], 256); }
        __syncthreads();

        // gates + state update + cur_c into c_star[384:768]
        {
            int j = tid;
#pragma unroll
            for (int r = 0; r < 2; ++r) {
                float iv = sZ[r][j], fv = sZ[r][256 + j], gv = sZ[r][512 + j], ov = sZ[r][768 + j];
                float c2 = sigm(fv) * sTc[r][j] + sigm(iv) * tanh_fast(gv);
                float h2 = sigm(ov) * tanh_fast(c2);
                sTc[r][j] = c2; sTh[r][j] = h2; sCs[r][384 + j] = c2;
            }
            if (tid < 128) {
                int r = tid >> 6, jj = tid & 63;
                float iv = sZa[r][jj], fv = sZa[r][64 + jj], gv = sZa[r][128 + jj], ov = sZa[r][192 + jj];
                float c2 = sigm(fv) * sAc[r][jj] + sigm(iv) * tanh_fast(gv);
                float h2 = sigm(ov) * tanh_fast(c2);
                sAc[r][jj] = c2; sAh[r][jj] = h2; sCs[r][640 + jj] = c2;
            } else {
                int r = (tid - 128) >> 6, jj = tid & 63;
                float iv = sZv[r][jj], fv = sZv[r][64 + jj], gv = sZv[r][128 + jj], ov = sZv[r][192 + jj];
                float c2 = sigm(fv) * sVc[r][jj] + sigm(iv) * tanh_fast(gv);
                float h2 = sigm(ov) * tanh_fast(c2);
                sVc[r][jj] = c2; sVh[r][jj] = h2; sCs[r][704 + jj] = c2;
            }
        }
        __syncthreads();

        // attn1 layer1 (relu)
        { Part p[1] = {{&sCs[0][0], ATTN_D, 768}};
          gemmT<2, 1>(p, 1, wsb + OFF_A1W1, 512, a1b1, &sHid[0][0], 512); }
        __syncthreads();
        // attn1 layer2 -> scores
        { Part p[1] = {{&sHid[0][0], 512, 512}};
          gemmT<3, 0>(p, 1, wsb + OFF_A1W2, 768, a1b2, &sZ[0][0], 1024); }
        __syncthreads();

        // softmax (per row, one wave each) + attended = attn * c_star (in place)
        {
            int wv = tid >> 6, ln = tid & 63;
            if (wv < 2) {
                float mx = -3.0e38f;
                for (int i = ln; i < 768; i += 64) mx = fmaxf(mx, sZ[wv][i]);
                for (int o = 32; o; o >>= 1) mx = fmaxf(mx, __shfl_xor(mx, o));
                float sum = 0.f;
                for (int i = ln; i < 768; i += 64) { float e = __expf(sZ[wv][i] - mx); sZ[wv][i] = e; sum += e; }
                for (int o = 32; o; o >>= 1) sum += __shfl_xor(sum, o);
                if (ln == 0) sRed[wv] = 1.f / sum;
            }
        }
        __syncthreads();
        for (int i = tid; i < 2 * 768; i += 256) {
            int r = i / 768, c = i - r * 768;
            sCs[r][c] = sZ[r][c] * sRed[r] * sCs[r][c];
        }
        __syncthreads();

        // attn2 layer1 (relu)
        { Part p[1] = {{&sCs[0][0], ATTN_D, 768}};
          gemmT<2, 1>(p, 1, wsb + OFF_A2W1, 512, a2b1, &sHid[0][0], 512); }
        __syncthreads();
        // attn2 layer2 -> c_hat (tanh)
        { Part p[1] = {{&sHid[0][0], 512, 512}};
          gemmT<1, 2>(p, 1, wsb + OFF_A2W2, 256, a2b2, &sChat[0][0], 256); }
        // gates layer1 (both = [attended, m]) -> hidg (relu), packed g1|g2  (no sync needed: disjoint buffers)
        { Part p[2] = {{&sCs[0][0], ATTN_D, 768}, {&sM[0][0], MEM_D, 256}};
          gemmT<4, 1>(p, 2, wsb + OFF_GW1, 1024, wsf, &sZ[0][0], 1024); }
        __syncthreads();
        // gates layer2 (block-diagonal packed) -> [gam1_raw | gam2_raw]
        { Part p[1] = {{&sZ[0][0], 1024, 1024}};
          gemmT<2, 0>(p, 1, wsb + OFF_GW2, 512, wsf + 1024, &sHid[0][0], 512); }
        __syncthreads();

        // memory update
        {
            int j = tid;
#pragma unroll
            for (int r = 0; r < 2; ++r) {
                float g1v = sigm(sHid[r][j]);
                float g2v = sigm(sHid[r][256 + j]);
                sM[r][j] = g1v * sM[r][j] + g2v * sChat[r][j];
            }
        }
        __syncthreads();
    }

    // output head: last_h = [th, ah, vh, m]
    { Part p[4] = {{&sTh[0][0], 256, 256}, {&sAh[0][0], 64, 64},
                   {&sVh[0][0], 64, 64}, {&sM[0][0], 256, 256}};
      gemmT<2, 1>(p, 4, wsb + OFF_OW1, 512, ob1, &sHid[0][0], 512); }
    __syncthreads();
    {
        sR[0][tid] = sHid[0][tid] * ow2[tid] + sHid[0][256 + tid] * ow2[256 + tid];
        sR[1][tid] = sHid[1][tid] * ow2[tid] + sHid[1][256 + tid] * ow2[256 + tid];
        __syncthreads();
        for (int s = 128; s > 0; s >>= 1) {
            if (tid < s) { sR[0][tid] += sR[0][tid + s]; sR[1][tid] += sR[1][tid + s]; }
            __syncthreads();
        }
        if (tid == 0) {
            out[row0]     = sR[0][0] + ob2[0];
            out[row0 + 1] = sR[1][0] + ob2[0];
        }
    }
}

extern "C" void kernel_launch(void* const* d_in, const int* in_sizes, int n_in,
                              void* d_out, int out_size, void* d_ws, size_t ws_size,
                              hipStream_t stream)
{
    const float* x_p  = (const float*)d_in[0];
    const float* c_t  = (const float*)d_in[1];
    const float* c_a  = (const float*)d_in[2];
    const float* c_v  = (const float*)d_in[3];
    const float* memp = (const float*)d_in[4];

    unsigned short* wsb = (unsigned short*)d_ws;
    float* wsf = (float*)((char*)d_ws + (size_t)BF_TOTAL * 2);
    // needs ~7.7 MB of workspace

    // zero block-diagonal gw2 region first
    hipMemsetAsync((char*)d_ws + (size_t)OFF_GW2 * 2, 0, (size_t)1024 * 512 * 2, stream);

    auto T = [&](const void* src, long off, int N, int K, int stride, int ro, int co) {
        long total = (long)N * K;
        int blocks = (int)((total + 255) / 256);
        hipLaunchKernelGGL(k_transpose, dim3(blocks), dim3(256), 0, stream,
                           (const float*)src, wsb + off, N, K, stride, ro, co);
    };
    T(d_in[5],  OFF_TWI,  1024, 300, 1024, 0, 0);   // t_Wi
    T(d_in[6],  OFF_TWH,  1024, 256, 1024, 0, 0);   // t_Wh
    T(d_in[8],  OFF_AWI,  256,  74,  256,  0, 0);   // a_Wi
    T(d_in[9],  OFF_AWH,  256,  64,  256,  0, 0);   // a_Wh
    T(d_in[11], OFF_VWI,  256,  36,  256,  0, 0);   // v_Wi
    T(d_in[12], OFF_VWH,  256,  64,  256,  0, 0);   // v_Wh
    T(d_in[14], OFF_A1W1, 512,  768, 512,  0, 0);   // attn1_w1
    T(d_in[16], OFF_A1W2, 768,  512, 768,  0, 0);   // attn1_w2
    T(d_in[18], OFF_A2W1, 512,  768, 512,  0, 0);   // attn2_w1
    T(d_in[20], OFF_A2W2, 256,  512, 256,  0, 0);   // attn2_w2
    T(d_in[22], OFF_GW1,  512, 1024, 1024, 0, 0);   // g1_w1 -> cols 0-511
    T(d_in[26], OFF_GW1,  512, 1024, 1024, 0, 512); // g2_w1 -> cols 512-1023
    T(d_in[24], OFF_GW2,  256,  512, 512,  0, 0);   // g1_w2 -> block (0,0)
    T(d_in[28], OFF_GW2,  256,  512, 512,  512, 256); // g2_w2 -> block (512,256)
    T(d_in[30], OFF_OW1,  512,  640, 512,  0, 0);   // out_w1

    hipLaunchKernelGGL(k_packbias, dim3(6), dim3(256), 0, stream,
                       (const float*)d_in[23], (const float*)d_in[27],
                       (const float*)d_in[25], (const float*)d_in[29], wsf);

    hipLaunchKernelGGL(fused_rnn, dim3(256), dim3(256), 0, stream,
                       x_p, c_t, c_a, c_v, memp,
                       (const float*)d_in[7],  (const float*)d_in[10], (const float*)d_in[13],
                       (const float*)d_in[15], (const float*)d_in[17],
                       (const float*)d_in[19], (const float*)d_in[21],
                       (const float*)d_in[31], (const float*)d_in[32], (const float*)d_in[33],
                       wsb, wsf, (float*)d_out);
}

// Round 3
// 51966.095 us; speedup vs baseline: 1.9994x; 1.9994x over previous
//
#include <hip/hip_runtime.h>
#include <hip/hip_bf16.h>

// ---------------- dims ----------------
#define X_IN_D 410
#define T_STEPS_D 128
#define NBATCH 512

// ws layout (bf16 element offsets). Weights stored TRANSPOSED: WT[k][n] = W[n][k].
#define OFF_TWI   0L         // [556][1024] rows 0-299 t_Wi^T, 300-555 t_Wh^T
#define OFF_AWI   569344L    // [138][256]  rows 0-73 a_Wi^T, 74-137 a_Wh^T
#define OFF_VWI   604672L    // [100][256]  rows 0-35 v_Wi^T, 36-99 v_Wh^T
#define OFF_A1W1  630272L    // [768][512]
#define OFF_A1W2  1023488L   // [512][768]
#define OFF_A2W1  1416704L   // [768][512]
#define OFF_A2W2  1809920L   // [512][256]
#define OFF_GW1   1940992L   // [1024][1024] cols 0-511 g1_w1^T, 512-1023 g2_w1^T
#define OFF_GW2   2989568L   // [512][512] packed: cols 0-255 g1_w2^T, 256-511 g2_w2^T
#define OFF_OW1   3251712L   // [640][512]
#define BF_TOTAL  3579392L   // bf16 elements; fp32 packed biases follow (1536 floats)

__device__ __forceinline__ float bf2f(unsigned short h) {
    union { unsigned u; float f; } v; v.u = ((unsigned)h) << 16; return v.f;
}
__device__ __forceinline__ float sigm(float x) { return 1.f / (1.f + __expf(-x)); }
__device__ __forceinline__ float tanh_fast(float x) {
    float e = __expf(2.f * x);
    return 1.f - 2.f / (e + 1.f);
}

struct Part { const float* act; int K; int stride; };

// 4-row GEMM: out[r][n0..n0+CB) for r=0..3. WT bf16 [sum(K)][N] row-major.
// Caller guarantees (active threads)*CB == N and guards tid range.
// MODE: 0 none, 1 relu, 2 tanh
template<int N, int CB, int MODE>
__device__ __forceinline__ void gemm4(const Part* parts, int np,
                                      const unsigned short* __restrict__ WT,
                                      const float* __restrict__ bias,
                                      float* __restrict__ out, int outStride, int tid)
{
    const int n0 = tid * CB;
    float acc[4][CB];
#pragma unroll
    for (int c = 0; c < CB; ++c) {
        float b = bias[n0 + c];
#pragma unroll
        for (int r = 0; r < 4; ++r) acc[r][c] = b;
    }
    const unsigned short* w = WT + n0;
    for (int p = 0; p < np; ++p) {
        const float* a = parts[p].act;
        const int st = parts[p].stride;
        const int K = parts[p].K;
        int k = 0;
        for (; k + 8 <= K; k += 8) {
            unsigned u[8];
            unsigned short us[8];
            if constexpr (CB == 2) {
#pragma unroll
                for (int kk = 0; kk < 8; ++kk) u[kk] = *(const unsigned*)(w + kk * N);
            } else {
#pragma unroll
                for (int kk = 0; kk < 8; ++kk) us[kk] = w[kk * N];
            }
            float4 xa[4], xb[4];
#pragma unroll
            for (int r = 0; r < 4; ++r) {
                xa[r] = *(const float4*)(a + r * st + k);
                xb[r] = *(const float4*)(a + r * st + k + 4);
            }
#pragma unroll
            for (int kk = 0; kk < 8; ++kk) {
                float wv[CB];
                if constexpr (CB == 2) {
                    wv[0] = bf2f((unsigned short)u[kk]);
                    wv[1] = bf2f((unsigned short)(u[kk] >> 16));
                } else {
                    wv[0] = bf2f(us[kk]);
                }
#pragma unroll
                for (int r = 0; r < 4; ++r) {
                    float x = (kk < 4) ? ((const float*)&xa[r])[kk]
                                       : ((const float*)&xb[r])[kk - 4];
#pragma unroll
                    for (int c = 0; c < CB; ++c) acc[r][c] += x * wv[c];
                }
            }
            w += 8 * N;
        }
        for (; k < K; ++k) {
            float wv[CB];
            if constexpr (CB == 2) {
                unsigned u = *(const unsigned*)w;
                wv[0] = bf2f((unsigned short)u);
                wv[1] = bf2f((unsigned short)(u >> 16));
            } else {
                wv[0] = bf2f(w[0]);
            }
#pragma unroll
            for (int r = 0; r < 4; ++r) {
                float x = a[r * st + k];
#pragma unroll
                for (int c = 0; c < CB; ++c) acc[r][c] += x * wv[c];
            }
            w += N;
        }
    }
#pragma unroll
    for (int r = 0; r < 4; ++r) {
#pragma unroll
        for (int c = 0; c < CB; ++c) {
            float v = acc[r][c];
            if constexpr (MODE == 1) v = fmaxf(v, 0.f);
            if constexpr (MODE == 2) v = tanh_fast(v);
            out[r * outStride + n0 + c] = v;
        }
    }
}

// -------- prologue kernels --------
__global__ void k_transpose(const float* __restrict__ src, unsigned short* __restrict__ dst,
                            int N, int K, int stride, int rowOff, int colOff)
{
    long i = (long)blockIdx.x * 256 + threadIdx.x;
    if (i >= (long)N * K) return;
    int n = (int)(i / K);
    int k = (int)(i - (long)n * K);
    __hip_bfloat16 b = __float2bfloat16(src[i]);
    dst[(long)(k + rowOff) * stride + colOff + n] = *reinterpret_cast<unsigned short*>(&b);
}

__global__ void k_packbias(const float* __restrict__ g1b1, const float* __restrict__ g2b1,
                           const float* __restrict__ g1b2, const float* __restrict__ g2b2,
                           float* __restrict__ gb)
{
    int i = blockIdx.x * 256 + threadIdx.x;
    if (i < 512) gb[i] = g1b1[i];
    else if (i < 1024) gb[i] = g2b1[i - 512];
    else if (i < 1280) gb[i] = g1b2[i - 1024];
    else if (i < 1536) gb[i] = g2b2[i - 1280];
}

// -------- main persistent kernel: one WG = 4 batch rows, 512 threads, 128 WGs --------
__global__ __launch_bounds__(512)
void fused_rnn(const float* __restrict__ x_p,
               const float* __restrict__ c_t0, const float* __restrict__ c_a0,
               const float* __restrict__ c_v0, const float* __restrict__ mem0,
               const float* __restrict__ t_b, const float* __restrict__ a_b,
               const float* __restrict__ v_b,
               const float* __restrict__ a1b1, const float* __restrict__ a1b2,
               const float* __restrict__ a2b1, const float* __restrict__ a2b2,
               const float* __restrict__ ob1, const float* __restrict__ ow2,
               const float* __restrict__ ob2,
               const unsigned short* __restrict__ wsb, const float* __restrict__ wsf,
               float* __restrict__ out)
{
    const int tid = threadIdx.x;
    const int row0 = blockIdx.x * 4;

    __shared__ alignas(16) float sX[4][424];     // xt @0(300), xa @304(74), xv @384(36)
    __shared__ alignas(16) float sZ[4][1024];    // t-LSTM z / attn1 scores / gates hidden
    __shared__ alignas(16) float sZa[4][256];
    __shared__ alignas(16) float sZv[4][256];
    __shared__ alignas(16) float sTc[4][256];
    __shared__ alignas(16) float sTh[4][256];
    __shared__ alignas(16) float sAc[4][64];
    __shared__ alignas(16) float sAh[4][64];
    __shared__ alignas(16) float sVc[4][64];
    __shared__ alignas(16) float sVh[4][64];
    __shared__ alignas(16) float sM[4][256];
    __shared__ alignas(16) float sCs[4][768];    // c_star, then attended (in place)
    __shared__ alignas(16) float sHid[4][512];   // relu hiddens
    __shared__ alignas(16) float sG[4][512];     // [g1raw | g2raw]
    __shared__ alignas(16) float sCp[2][4][256]; // split-K partials of attn2-l2
    __shared__ float sRed[4];
    __shared__ float sRed2[8][4];

    // init states
    for (int i = tid; i < 4 * 256; i += 512) {
        int r = i >> 8, j = i & 255;
        sTc[r][j] = c_t0[(row0 + r) * 256 + j];
        sTh[r][j] = 0.f;
        sM[r][j] = mem0[(row0 + r) * 256 + j];
    }
    for (int i = tid; i < 4 * 64; i += 512) {
        int r = i >> 6, j = i & 63;
        sAc[r][j] = c_a0[(row0 + r) * 64 + j]; sAh[r][j] = 0.f;
        sVc[r][j] = c_v0[(row0 + r) * 64 + j]; sVh[r][j] = 0.f;
    }
    __syncthreads();

    for (int t = 0; t < T_STEPS_D; ++t) {
        // ---- stage 1: load x (padded), copy pre_c into c_star[0:384] ----
        const float* xb = x_p + ((long)t * NBATCH + row0) * X_IN_D;
        for (int i = tid; i < 4 * X_IN_D; i += 512) {
            int r = i / X_IN_D, c = i - r * X_IN_D;
            int lc = (c < 300) ? c : ((c < 374) ? c + 4 : c + 10);
            sX[r][lc] = xb[r * X_IN_D + c];
        }
        for (int i = tid; i < 4 * 384; i += 512) {
            int r = i / 384, c = i - r * 384;
            sCs[r][c] = (c < 256) ? sTc[r][c] : ((c < 320) ? sAc[r][c - 256] : sVc[r][c - 320]);
        }
        __syncthreads();

        // ---- stage 2: LSTM pre-activations ----
        {
            Part p[2];
            p[0].act = &sX[0][0];  p[0].K = 300; p[0].stride = 424;
            p[1].act = &sTh[0][0]; p[1].K = 256; p[1].stride = 256;
            gemm4<1024, 2, 0>(p, 2, wsb + OFF_TWI, t_b, &sZ[0][0], 1024, tid);
        }
        if (tid < 256) {
            Part p[2];
            p[0].act = &sX[0][304]; p[0].K = 74; p[0].stride = 424;
            p[1].act = &sAh[0][0];  p[1].K = 64; p[1].stride = 64;
            gemm4<256, 1, 0>(p, 2, wsb + OFF_AWI, a_b, &sZa[0][0], 256, tid);
        } else {
            Part p[2];
            p[0].act = &sX[0][384]; p[0].K = 36; p[0].stride = 424;
            p[1].act = &sVh[0][0];  p[1].K = 64; p[1].stride = 64;
            gemm4<256, 1, 0>(p, 2, wsb + OFF_VWI, v_b, &sZv[0][0], 256, tid - 256);
        }
        __syncthreads();

        // ---- stage 3: gates + state update + cur_c into c_star[384:768] ----
        {
            int j = tid & 255;
            for (int r = tid >> 8; r < 4; r += 2) {
                float iv = sZ[r][j], fv = sZ[r][256 + j], gv = sZ[r][512 + j], ov = sZ[r][768 + j];
                float c2 = sigm(fv) * sTc[r][j] + sigm(iv) * tanh_fast(gv);
                float h2 = sigm(ov) * tanh_fast(c2);
                sTc[r][j] = c2; sTh[r][j] = h2; sCs[r][384 + j] = c2;
            }
            int cell = tid >> 8, r2 = (tid >> 6) & 3, j2 = tid & 63;
            if (cell == 0) {
                float iv = sZa[r2][j2], fv = sZa[r2][64 + j2], gv = sZa[r2][128 + j2], ov = sZa[r2][192 + j2];
                float c2 = sigm(fv) * sAc[r2][j2] + sigm(iv) * tanh_fast(gv);
                float h2 = sigm(ov) * tanh_fast(c2);
                sAc[r2][j2] = c2; sAh[r2][j2] = h2; sCs[r2][640 + j2] = c2;
            } else {
                float iv = sZv[r2][j2], fv = sZv[r2][64 + j2], gv = sZv[r2][128 + j2], ov = sZv[r2][192 + j2];
                float c2 = sigm(fv) * sVc[r2][j2] + sigm(iv) * tanh_fast(gv);
                float h2 = sigm(ov) * tanh_fast(c2);
                sVc[r2][j2] = c2; sVh[r2][j2] = h2; sCs[r2][704 + j2] = c2;
            }
        }
        __syncthreads();

        // ---- stage 4: attn1 ----
        {
            Part p[1];
            p[0].act = &sCs[0][0]; p[0].K = 768; p[0].stride = 768;
            gemm4<512, 1, 1>(p, 1, wsb + OFF_A1W1, a1b1, &sHid[0][0], 512, tid);
        }
        __syncthreads();
        if (tid < 384) {
            Part p[1];
            p[0].act = &sHid[0][0]; p[0].K = 512; p[0].stride = 512;
            gemm4<768, 2, 0>(p, 1, wsb + OFF_A1W2, a1b2, &sZ[0][0], 1024, tid);
        }
        __syncthreads();

        // ---- stage 5: softmax (wave r -> row r) + attended (in place) ----
        {
            int wv = tid >> 6, ln = tid & 63;
            if (wv < 4) {
                float mx = -3.0e38f;
                for (int i = ln; i < 768; i += 64) mx = fmaxf(mx, sZ[wv][i]);
                for (int o = 32; o; o >>= 1) mx = fmaxf(mx, __shfl_xor(mx, o));
                float sum = 0.f;
                for (int i = ln; i < 768; i += 64) { float e = __expf(sZ[wv][i] - mx); sZ[wv][i] = e; sum += e; }
                for (int o = 32; o; o >>= 1) sum += __shfl_xor(sum, o);
                if (ln == 0) sRed[wv] = 1.f / sum;
            }
        }
        __syncthreads();
        for (int i = tid; i < 4 * 768; i += 512) {
            int r = i / 768, c = i - r * 768;
            sCs[r][c] = sZ[r][c] * sRed[r] * sCs[r][c];
        }
        __syncthreads();

        // ---- stage 6: attn2-l1 (-> sHid) and gates-l1 (-> sZ), same inputs, disjoint outputs ----
        {
            Part p[1];
            p[0].act = &sCs[0][0]; p[0].K = 768; p[0].stride = 768;
            gemm4<512, 1, 1>(p, 1, wsb + OFF_A2W1, a2b1, &sHid[0][0], 512, tid);
        }
        {
            Part p[2];
            p[0].act = &sCs[0][0]; p[0].K = 768; p[0].stride = 768;
            p[1].act = &sM[0][0];  p[1].K = 256; p[1].stride = 256;
            gemm4<1024, 2, 1>(p, 2, wsb + OFF_GW1, wsf, &sZ[0][0], 1024, tid);
        }
        __syncthreads();

        // ---- stage 7: attn2-l2 split-K (-> sCp) and gates-l2 halves (-> sG) ----
        {
            int col = tid & 255, kh = tid >> 8;
            const unsigned short* w = wsb + OFF_A2W2 + (long)(kh * 256) * 256 + col;
            const float* h = &sHid[0][kh * 256];
            float a0 = 0.f, a1 = 0.f, a2 = 0.f, a3 = 0.f;
#pragma unroll 8
            for (int k = 0; k < 256; ++k) {
                float wv = bf2f(w[0]); w += 256;
                a0 += h[k] * wv; a1 += h[512 + k] * wv;
                a2 += h[1024 + k] * wv; a3 += h[1536 + k] * wv;
            }
            sCp[kh][0][col] = a0; sCp[kh][1][col] = a1;
            sCp[kh][2][col] = a2; sCp[kh][3][col] = a3;
        }
        {
            int col = tid & 255, half = tid >> 8;
            const unsigned short* w = wsb + OFF_GW2 + half * 256 + col;
            const float* zc = &sZ[0][half * 512];
            float b = wsf[1024 + half * 256 + col];
            float a0 = b, a1 = b, a2 = b, a3 = b;
#pragma unroll 8
            for (int k = 0; k < 512; ++k) {
                float wv = bf2f(w[0]); w += 512;
                a0 += zc[k] * wv; a1 += zc[1024 + k] * wv;
                a2 += zc[2048 + k] * wv; a3 += zc[3072 + k] * wv;
            }
            sG[0][half * 256 + col] = a0; sG[1][half * 256 + col] = a1;
            sG[2][half * 256 + col] = a2; sG[3][half * 256 + col] = a3;
        }
        __syncthreads();

        // ---- stage 8: memory update ----
        {
            int j = tid & 255;
            for (int r = tid >> 8; r < 4; r += 2) {
                float g1v = sigm(sG[r][j]);
                float g2v = sigm(sG[r][256 + j]);
                float ch = tanh_fast(sCp[0][r][j] + sCp[1][r][j] + a2b2[j]);
                sM[r][j] = g1v * sM[r][j] + g2v * ch;
            }
        }
        __syncthreads();
    }

    // ---- output head: last_h = [th, ah, vh, m] ----
    {
        Part p[4];
        p[0].act = &sTh[0][0]; p[0].K = 256; p[0].stride = 256;
        p[1].act = &sAh[0][0]; p[1].K = 64;  p[1].stride = 64;
        p[2].act = &sVh[0][0]; p[2].K = 64;  p[2].stride = 64;
        p[3].act = &sM[0][0];  p[3].K = 256; p[3].stride = 256;
        gemm4<512, 1, 1>(p, 4, wsb + OFF_OW1, ob1, &sHid[0][0], 512, tid);
    }
    __syncthreads();
    {
        float wv2 = ow2[tid];
        float pr[4];
#pragma unroll
        for (int r = 0; r < 4; ++r) pr[r] = sHid[r][tid] * wv2;
#pragma unroll
        for (int o = 32; o; o >>= 1) {
#pragma unroll
            for (int r = 0; r < 4; ++r) pr[r] += __shfl_xor(pr[r], o);
        }
        int wvid = tid >> 6, ln = tid & 63;
        if (ln == 0) {
#pragma unroll
            for (int r = 0; r < 4; ++r) sRed2[wvid][r] = pr[r];
        }
        __syncthreads();
        if (tid < 4) {
            float s = 0.f;
#pragma unroll
            for (int w = 0; w < 8; ++w) s += sRed2[w][tid];
            out[row0 + tid] = s + ob2[0];
        }
    }
}

extern "C" void kernel_launch(void* const* d_in, const int* in_sizes, int n_in,
                              void* d_out, int out_size, void* d_ws, size_t ws_size,
                              hipStream_t stream)
{
    const float* x_p  = (const float*)d_in[0];
    const float* c_t  = (const float*)d_in[1];
    const float* c_a  = (const float*)d_in[2];
    const float* c_v  = (const float*)d_in[3];
    const float* memp = (const float*)d_in[4];

    unsigned short* wsb = (unsigned short*)d_ws;
    float* wsf = (float*)((char*)d_ws + (size_t)BF_TOTAL * 2);
    // total ws use: ~7.17 MB

    auto T = [&](const void* src, long off, int N, int K, int stride, int ro, int co) {
        long total = (long)N * K;
        int blocks = (int)((total + 255) / 256);
        hipLaunchKernelGGL(k_transpose, dim3(blocks), dim3(256), 0, stream,
                           (const float*)src, wsb + off, N, K, stride, ro, co);
    };
    T(d_in[5],  OFF_TWI,  1024, 300, 1024, 0,   0);   // t_Wi
    T(d_in[6],  OFF_TWI,  1024, 256, 1024, 300, 0);   // t_Wh
    T(d_in[8],  OFF_AWI,  256,  74,  256,  0,   0);   // a_Wi
    T(d_in[9],  OFF_AWI,  256,  64,  256,  74,  0);   // a_Wh
    T(d_in[11], OFF_VWI,  256,  36,  256,  0,   0);   // v_Wi
    T(d_in[12], OFF_VWI,  256,  64,  256,  36,  0);   // v_Wh
    T(d_in[14], OFF_A1W1, 512,  768, 512,  0,   0);   // attn1_w1
    T(d_in[16], OFF_A1W2, 768,  512, 768,  0,   0);   // attn1_w2
    T(d_in[18], OFF_A2W1, 512,  768, 512,  0,   0);   // attn2_w1
    T(d_in[20], OFF_A2W2, 256,  512, 256,  0,   0);   // attn2_w2
    T(d_in[22], OFF_GW1,  512, 1024, 1024, 0,   0);   // g1_w1 -> cols 0-511
    T(d_in[26], OFF_GW1,  512, 1024, 1024, 0,   512); // g2_w1 -> cols 512-1023
    T(d_in[24], OFF_GW2,  256,  512, 512,  0,   0);   // g1_w2 -> cols 0-255
    T(d_in[28], OFF_GW2,  256,  512, 512,  0,   256); // g2_w2 -> cols 256-511
    T(d_in[30], OFF_OW1,  512,  640, 512,  0,   0);   // out_w1

    hipLaunchKernelGGL(k_packbias, dim3(6), dim3(256), 0, stream,
                       (const float*)d_in[23], (const float*)d_in[27],
                       (const float*)d_in[25], (const float*)d_in[29], wsf);

    hipLaunchKernelGGL(fused_rnn, dim3(128), dim3(512), 0, stream,
                       x_p, c_t, c_a, c_v, memp,
                       (const float*)d_in[7],  (const float*)d_in[10], (const float*)d_in[13],
                       (const float*)d_in[15], (const float*)d_in[17],
                       (const float*)d_in[19], (const float*)d_in[21],
                       (const float*)d_in[31], (const float*)d_in[32], (const float*)d_in[33],
                       wsb, wsf, (float*)d_out);
}

// Round 5
// 21308.659 us; speedup vs baseline: 4.8760x; 2.4387x over previous
//
#include <hip/hip_runtime.h>
#include <hip/hip_bf16.h>
#include <hip/hip_fp16.h>

typedef unsigned int u32;
typedef __fp16 h2t __attribute__((ext_vector_type(2)));

// ---------------- dims ----------------
#define T_STEPS_D 128
#define NBATCH 512

// ws layout (u32 element offsets). Weights f16, k-paired: W2[k/2][n] u32 = (f16 W[k][n], f16 W[k+1][n])
#define OFF_TWI   0L         // K=556 (300 t_Wi + 256 t_Wh), N=1024
#define OFF_AWI   284672L    // K=138 (74+64), N=256
#define OFF_VWI   302336L    // K=100 (36+64), N=256
#define OFF_A1W1  315136L    // K=768, N=512
#define OFF_A1W2  511744L    // K=512, N=768
#define OFF_A2W1  708352L    // K=768, N=512
#define OFF_A2W2  904960L    // K=512, N=256
#define OFF_GW1   970496L    // K=1024, N=1024 (cols 0-511 g1_w1, 512-1023 g2_w1)
#define OFF_GW2   1494784L   // K=512, N=512 (cols 0-255 g1_w2 [from z:0-511], 256-511 g2_w2 [from z:512-1023])
#define OFF_OW1   1625856L   // K=640, N=512
#define U32_TOTAL 1789696L   // u32 elements; fp32 packed biases follow (1536 floats)

__device__ __forceinline__ float sigm(float x) { return 1.f / (1.f + __expf(-x)); }
__device__ __forceinline__ float tanh_fast(float x) {
    float e = __expf(2.f * x);
    return 1.f - 2.f / (e + 1.f);
}
__device__ __forceinline__ float dot2(u32 a, u32 b, float c) {
    union { u32 u; h2t h; } x, y; x.u = a; y.u = b;
#if __has_builtin(__builtin_amdgcn_fdot2)
    return __builtin_amdgcn_fdot2(x.h, y.h, c, false);
#else
    c += (float)x.h[0] * (float)y.h[0];
    c += (float)x.h[1] * (float)y.h[1];
    return c;
#endif
}
__device__ __forceinline__ u32 pk2(float a, float b) {
    union { h2t h; u32 u; } z;
    z.h = __builtin_amdgcn_cvt_pkrtz(a, b);
    return z.u;
}

struct PP { const u32* a; int k2; int stride; };

// 4-row f16-pair GEMM. Each thread: NC output cols at n0=tid*NC (fp cols == u32 cols).
// WT: u32 [sum(K2)][N]. Activations packed u32 (2 f16) per k-pair, row stride in u32.
// OUTP: 0 = fp32 out (outF, stride fp32), 1 = packed u32 out (outU, stride u32; NC==1 uses shfl pair).
template<int NC, bool RELU, int OUTP>
__device__ __forceinline__ void gemmP(const PP* ps, int np,
    const u32* __restrict__ WT, int N, const float* __restrict__ bias,
    float* __restrict__ outF, u32* __restrict__ outU, int outStride, int tid)
{
    const int n0 = tid * NC;
    float acc[4][NC];
#pragma unroll
    for (int r = 0; r < 4; ++r)
#pragma unroll
        for (int c = 0; c < NC; ++c) acc[r][c] = 0.f;

    const u32* w = WT + n0;
    for (int p = 0; p < np; ++p) {
        const u32* a0 = ps[p].a;
        const int st = ps[p].stride;
        const int K2 = ps[p].k2;
        const int nb = K2 >> 3;
        u32 cw[8 * NC], nw[8 * NC];
        if (nb > 0) {
#pragma unroll
            for (int u = 0; u < 8; ++u)
#pragma unroll
                for (int c = 0; c < NC; ++c) cw[u * NC + c] = w[u * N + c];
            w += 8 * N;
        }
        int kb = 0;
        for (int b = 0; b < nb; ++b) {
            const bool last = (b == nb - 1);
            if (!last) {   // prefetch next weight block while computing current
#pragma unroll
                for (int u = 0; u < 8; ++u)
#pragma unroll
                    for (int c = 0; c < NC; ++c) nw[u * NC + c] = w[u * N + c];
                w += 8 * N;
            }
#pragma unroll
            for (int hb = 0; hb < 2; ++hb) {
                uint4 av[4];
#pragma unroll
                for (int r = 0; r < 4; ++r)
                    av[r] = *(const uint4*)(a0 + r * st + kb + hb * 4);
#pragma unroll
                for (int u = 0; u < 4; ++u) {
#pragma unroll
                    for (int r = 0; r < 4; ++r) {
                        const u32 aa = (&av[r].x)[u];
#pragma unroll
                        for (int c = 0; c < NC; ++c)
                            acc[r][c] = dot2(cw[(hb * 4 + u) * NC + c], aa, acc[r][c]);
                    }
                }
            }
            if (!last) {
#pragma unroll
                for (int i = 0; i < 8 * NC; ++i) cw[i] = nw[i];
            }
            kb += 8;
        }
        for (int k2 = nb * 8; k2 < K2; ++k2) {   // tail (<8 pairs)
            u32 wv[NC];
#pragma unroll
            for (int c = 0; c < NC; ++c) wv[c] = w[c];
            w += N;
#pragma unroll
            for (int r = 0; r < 4; ++r) {
                u32 aa = a0[r * st + k2];
#pragma unroll
                for (int c = 0; c < NC; ++c)
                    acc[r][c] = dot2(wv[c], aa, acc[r][c]);
            }
        }
    }
#pragma unroll
    for (int r = 0; r < 4; ++r) {
        float v[NC];
#pragma unroll
        for (int c = 0; c < NC; ++c) {
            v[c] = acc[r][c] + (bias ? bias[n0 + c] : 0.f);
            if (RELU) v[c] = fmaxf(v[c], 0.f);
        }
        if constexpr (OUTP == 0) {
#pragma unroll
            for (int c = 0; c < NC; ++c) outF[r * outStride + n0 + c] = v[c];
        } else {
            if constexpr (NC == 2) {
                outU[r * outStride + (n0 >> 1)] = pk2(v[0], v[1]);
            } else {
                float vo = __shfl_xor(v[0], 1);
                if ((tid & 1) == 0) outU[r * outStride + (n0 >> 1)] = pk2(v[0], vo);
            }
        }
    }
}

// -------- prologue kernels --------
__global__ void k_transpose(const float* __restrict__ src, unsigned short* __restrict__ dst,
                            int N, int K, int strideU, int rowOffK, int colOff)
{
    long i = (long)blockIdx.x * 256 + threadIdx.x;
    if (i >= (long)N * K) return;
    int n = (int)(i / K);
    int k = (int)(i - (long)n * K);
    __half h = __float2half(src[i]);
    int kk = k + rowOffK;
    long idx = (long)(kk >> 1) * (2L * strideU) + 2L * (colOff + n) + (kk & 1);
    dst[idx] = __half_as_ushort(h);
}

__global__ void k_packbias(const float* __restrict__ g1b1, const float* __restrict__ g2b1,
                           const float* __restrict__ g1b2, const float* __restrict__ g2b2,
                           float* __restrict__ gb)
{
    int i = blockIdx.x * 256 + threadIdx.x;
    if (i < 512) gb[i] = g1b1[i];
    else if (i < 1024) gb[i] = g2b1[i - 512];
    else if (i < 1280) gb[i] = g1b2[i - 1024];
    else if (i < 1536) gb[i] = g2b2[i - 1280];
}

// -------- main persistent kernel: one WG = 4 batch rows, 512 threads, 128 WGs --------
__global__ __launch_bounds__(512)
void fused_rnn(const float* __restrict__ x_p,
               const float* __restrict__ c_t0, const float* __restrict__ c_a0,
               const float* __restrict__ c_v0, const float* __restrict__ mem0,
               const float* __restrict__ t_b, const float* __restrict__ a_b,
               const float* __restrict__ v_b,
               const float* __restrict__ a1b1, const float* __restrict__ a1b2,
               const float* __restrict__ a2b1, const float* __restrict__ a2b2,
               const float* __restrict__ ob1, const float* __restrict__ ow2,
               const float* __restrict__ ob2,
               const u32* __restrict__ wsu, const float* __restrict__ wsf,
               float* __restrict__ out)
{
    const int tid = threadIdx.x;
    const int row0 = blockIdx.x * 4;

    // fp32 buffers (pointwise math)
    __shared__ alignas(16) float sZ[4][1024];
    __shared__ alignas(16) float sZa[4][256];
    __shared__ alignas(16) float sZv[4][256];
    __shared__ alignas(16) float sTc[4][256];
    __shared__ alignas(16) float sAc[4][64];
    __shared__ alignas(16) float sVc[4][64];
    __shared__ alignas(16) float sM[4][256];
    __shared__ alignas(16) float sCs[4][768];
    __shared__ alignas(16) float sG[4][512];
    __shared__ alignas(16) float sCp[2][4][256];
    __shared__ alignas(16) float sHid[4][512];
    // packed f16-pair buffers (GEMM inputs)
    __shared__ alignas(16) u32 pX[4][212];   // xt pairs 0-149, xa 152-188, xv 192-209
    __shared__ alignas(16) u32 pCs[4][384];  // c_star / attended
    __shared__ alignas(16) u32 pTh[4][128];
    __shared__ alignas(16) u32 pAh[4][32];
    __shared__ alignas(16) u32 pVh[4][32];
    __shared__ alignas(16) u32 pM[4][128];
    __shared__ alignas(16) u32 pHid[4][256];
    __shared__ alignas(16) u32 pZ[4][512];
    __shared__ float sRed[4];
    __shared__ float sRed2[8][4];

    // ---- init states ----
    for (int i = tid; i < 4 * 128; i += 512) {
        int r = i >> 7, j2 = i & 127, j = 2 * j2;
        float t0 = c_t0[(row0 + r) * 256 + j], t1 = c_t0[(row0 + r) * 256 + j + 1];
        float m0 = mem0[(row0 + r) * 256 + j], m1 = mem0[(row0 + r) * 256 + j + 1];
        sTc[r][j] = t0; sTc[r][j + 1] = t1;
        sM[r][j] = m0; sM[r][j + 1] = m1;
        pM[r][j2] = pk2(m0, m1);
        pTh[r][j2] = 0u;
    }
    for (int i = tid; i < 4 * 32; i += 512) {
        int r = i >> 5, j2 = i & 31, j = 2 * j2;
        sAc[r][j] = c_a0[(row0 + r) * 64 + j]; sAc[r][j + 1] = c_a0[(row0 + r) * 64 + j + 1];
        sVc[r][j] = c_v0[(row0 + r) * 64 + j]; sVc[r][j + 1] = c_v0[(row0 + r) * 64 + j + 1];
        pAh[r][j2] = 0u; pVh[r][j2] = 0u;
    }
    __syncthreads();

    for (int t = 0; t < T_STEPS_D; ++t) {
        // ---- stage 1: pack x, copy+pack pre_c ----
        const float* xb = x_p + ((long)t * NBATCH + row0) * 410;
        for (int i = tid; i < 4 * 205; i += 512) {
            int r = i / 205, p = i - r * 205;
            float2 v = *(const float2*)(xb + r * 410 + 2 * p);
            int dst = (p < 150) ? p : (p < 187 ? p + 2 : p + 5);
            pX[r][dst] = pk2(v.x, v.y);
        }
        for (int i = tid; i < 4 * 192; i += 512) {
            int r = i / 192, p = i - r * 192;
            float v0, v1; int c;
            if (p < 128) { c = 2 * p; v0 = sTc[r][c]; v1 = sTc[r][c + 1]; }
            else if (p < 160) { int j = 2 * (p - 128); c = 256 + j; v0 = sAc[r][j]; v1 = sAc[r][j + 1]; }
            else { int j = 2 * (p - 160); c = 320 + j; v0 = sVc[r][j]; v1 = sVc[r][j + 1]; }
            sCs[r][c] = v0; sCs[r][c + 1] = v1;
            pCs[r][p] = pk2(v0, v1);
        }
        __syncthreads();

        // ---- stage 2: LSTM pre-activations ----
        {
            PP p[2];
            p[0].a = &pX[0][0];  p[0].k2 = 150; p[0].stride = 212;
            p[1].a = &pTh[0][0]; p[1].k2 = 128; p[1].stride = 128;
            gemmP<2, false, 0>(p, 2, wsu + OFF_TWI, 1024, t_b, &sZ[0][0], nullptr, 1024, tid);
        }
        if (tid < 256) {
            PP p[2];
            p[0].a = &pX[0][152]; p[0].k2 = 37; p[0].stride = 212;
            p[1].a = &pAh[0][0];  p[1].k2 = 32; p[1].stride = 32;
            gemmP<1, false, 0>(p, 2, wsu + OFF_AWI, 256, a_b, &sZa[0][0], nullptr, 256, tid);
        } else {
            PP p[2];
            p[0].a = &pX[0][192]; p[0].k2 = 18; p[0].stride = 212;
            p[1].a = &pVh[0][0];  p[1].k2 = 32; p[1].stride = 32;
            gemmP<1, false, 0>(p, 2, wsu + OFF_VWI, 256, v_b, &sZv[0][0], nullptr, 256, tid - 256);
        }
        __syncthreads();

        // ---- stage 3: LSTM pointwise + pack th/ah/vh + cur_c ----
        {
            int r = tid >> 7, j2 = tid & 127, j = 2 * j2;
            float i0 = sZ[r][j], f0 = sZ[r][256 + j], g0 = sZ[r][512 + j], o0 = sZ[r][768 + j];
            float i1 = sZ[r][j + 1], f1 = sZ[r][257 + j], g1 = sZ[r][513 + j], o1 = sZ[r][769 + j];
            float c20 = sigm(f0) * sTc[r][j] + sigm(i0) * tanh_fast(g0);
            float c21 = sigm(f1) * sTc[r][j + 1] + sigm(i1) * tanh_fast(g1);
            float h20 = sigm(o0) * tanh_fast(c20);
            float h21 = sigm(o1) * tanh_fast(c21);
            sTc[r][j] = c20; sTc[r][j + 1] = c21;
            sCs[r][384 + j] = c20; sCs[r][385 + j] = c21;
            pTh[r][j2] = pk2(h20, h21);
            pCs[r][192 + j2] = pk2(c20, c21);
        }
        if (tid < 128) {
            int r = tid >> 5, j2 = tid & 31, j = 2 * j2;
            float i0 = sZa[r][j], f0 = sZa[r][64 + j], g0 = sZa[r][128 + j], o0 = sZa[r][192 + j];
            float i1 = sZa[r][j + 1], f1 = sZa[r][65 + j], g1 = sZa[r][129 + j], o1 = sZa[r][193 + j];
            float c20 = sigm(f0) * sAc[r][j] + sigm(i0) * tanh_fast(g0);
            float c21 = sigm(f1) * sAc[r][j + 1] + sigm(i1) * tanh_fast(g1);
            float h20 = sigm(o0) * tanh_fast(c20);
            float h21 = sigm(o1) * tanh_fast(c21);
            sAc[r][j] = c20; sAc[r][j + 1] = c21;
            sCs[r][640 + j] = c20; sCs[r][641 + j] = c21;
            pAh[r][j2] = pk2(h20, h21);
            pCs[r][320 + j2] = pk2(c20, c21);
        } else if (tid < 256) {
            int t2 = tid - 128;
            int r = t2 >> 5, j2 = t2 & 31, j = 2 * j2;
            float i0 = sZv[r][j], f0 = sZv[r][64 + j], g0 = sZv[r][128 + j], o0 = sZv[r][192 + j];
            float i1 = sZv[r][j + 1], f1 = sZv[r][65 + j], g1 = sZv[r][129 + j], o1 = sZv[r][193 + j];
            float c20 = sigm(f0) * sVc[r][j] + sigm(i0) * tanh_fast(g0);
            float c21 = sigm(f1) * sVc[r][j + 1] + sigm(i1) * tanh_fast(g1);
            float h20 = sigm(o0) * tanh_fast(c20);
            float h21 = sigm(o1) * tanh_fast(c21);
            sVc[r][j] = c20; sVc[r][j + 1] = c21;
            sCs[r][704 + j] = c20; sCs[r][705 + j] = c21;
            pVh[r][j2] = pk2(h20, h21);
            pCs[r][352 + j2] = pk2(c20, c21);
        }
        __syncthreads();

        // ---- stage 4a: attn1-l1 (relu) -> packed pHid ----
        {
            PP p[1];
            p[0].a = &pCs[0][0]; p[0].k2 = 384; p[0].stride = 384;
            gemmP<1, true, 1>(p, 1, wsu + OFF_A1W1, 512, a1b1, nullptr, &pHid[0][0], 256, tid);
        }
        __syncthreads();
        // ---- stage 4b: attn1-l2 -> sZ scores (fp32) ----
        if (tid < 384) {
            PP p[1];
            p[0].a = &pHid[0][0]; p[0].k2 = 256; p[0].stride = 256;
            gemmP<2, false, 0>(p, 1, wsu + OFF_A1W2, 768, a1b2, &sZ[0][0], nullptr, 1024, tid);
        }
        __syncthreads();

        // ---- stage 5: softmax + attended -> packed pCs ----
        {
            int wv = tid >> 6, ln = tid & 63;
            if (wv < 4) {
                float mx = -3.0e38f;
                for (int i = ln; i < 768; i += 64) mx = fmaxf(mx, sZ[wv][i]);
                for (int o = 32; o; o >>= 1) mx = fmaxf(mx, __shfl_xor(mx, o));
                float sum = 0.f;
                for (int i = ln; i < 768; i += 64) { float e = __expf(sZ[wv][i] - mx); sZ[wv][i] = e; sum += e; }
                for (int o = 32; o; o >>= 1) sum += __shfl_xor(sum, o);
                if (ln == 0) sRed[wv] = 1.f / sum;
            }
        }
        __syncthreads();
        for (int i = tid; i < 4 * 384; i += 512) {
            int r = i / 384, p = i - r * 384, c = 2 * p;
            float s = sRed[r];
            float e0 = sZ[r][c] * s * sCs[r][c];
            float e1 = sZ[r][c + 1] * s * sCs[r][c + 1];
            pCs[r][p] = pk2(e0, e1);
        }
        __syncthreads();

        // ---- stage 6: attn2-l1 -> pHid ; gates-l1 -> pZ ----
        {
            PP p[1];
            p[0].a = &pCs[0][0]; p[0].k2 = 384; p[0].stride = 384;
            gemmP<1, true, 1>(p, 1, wsu + OFF_A2W1, 512, a2b1, nullptr, &pHid[0][0], 256, tid);
        }
        {
            PP p[2];
            p[0].a = &pCs[0][0]; p[0].k2 = 384; p[0].stride = 384;
            p[1].a = &pM[0][0];  p[1].k2 = 128; p[1].stride = 128;
            gemmP<2, true, 1>(p, 2, wsu + OFF_GW1, 1024, wsf, nullptr, &pZ[0][0], 512, tid);
        }
        __syncthreads();

        // ---- stage 7: attn2-l2 split-K (-> sCp) ; gates-l2 halves (-> sG) ----
        {
            int kh = tid >> 8, st = tid & 255;
            PP p[1];
            p[0].a = &pHid[0][kh * 128]; p[0].k2 = 128; p[0].stride = 256;
            gemmP<1, false, 0>(p, 1, wsu + OFF_A2W2 + (long)kh * 128 * 256, 256, nullptr,
                               &sCp[kh][0][0], nullptr, 256, st);
        }
        {
            int half = tid >> 8, st = tid & 255;
            PP p[1];
            p[0].a = &pZ[0][half * 256]; p[0].k2 = 256; p[0].stride = 512;
            gemmP<1, false, 0>(p, 1, wsu + OFF_GW2 + half * 256, 512, wsf + 1024 + half * 256,
                               &sG[0][half * 256], nullptr, 512, st);
        }
        __syncthreads();

        // ---- stage 8: memory update ----
        {
            int r = tid >> 7, j2 = tid & 127, j = 2 * j2;
            float g10 = sigm(sG[r][j]),     g11 = sigm(sG[r][j + 1]);
            float g20 = sigm(sG[r][256 + j]), g21 = sigm(sG[r][257 + j]);
            float ch0 = tanh_fast(sCp[0][r][j] + sCp[1][r][j] + a2b2[j]);
            float ch1 = tanh_fast(sCp[0][r][j + 1] + sCp[1][r][j + 1] + a2b2[j + 1]);
            float m0 = g10 * sM[r][j] + g20 * ch0;
            float m1 = g11 * sM[r][j + 1] + g21 * ch1;
            sM[r][j] = m0; sM[r][j + 1] = m1;
            pM[r][j2] = pk2(m0, m1);
        }
        __syncthreads();
    }

    // ---- output head: last_h = [th, ah, vh, m] ----
    {
        PP p[4];
        p[0].a = &pTh[0][0]; p[0].k2 = 128; p[0].stride = 128;
        p[1].a = &pAh[0][0]; p[1].k2 = 32;  p[1].stride = 32;
        p[2].a = &pVh[0][0]; p[2].k2 = 32;  p[2].stride = 32;
        p[3].a = &pM[0][0];  p[3].k2 = 128; p[3].stride = 128;
        gemmP<1, true, 0>(p, 4, wsu + OFF_OW1, 512, ob1, &sHid[0][0], nullptr, 512, tid);
    }
    __syncthreads();
    {
        float wv2 = ow2[tid];
        float pr[4];
#pragma unroll
        for (int r = 0; r < 4; ++r) pr[r] = sHid[r][tid] * wv2;
#pragma unroll
        for (int o = 32; o; o >>= 1) {
#pragma unroll
            for (int r = 0; r < 4; ++r) pr[r] += __shfl_xor(pr[r], o);
        }
        int wvid = tid >> 6, ln = tid & 63;
        if (ln == 0) {
#pragma unroll
            for (int r = 0; r < 4; ++r) sRed2[wvid][r] = pr[r];
        }
        __syncthreads();
        if (tid < 4) {
            float s = 0.f;
#pragma unroll
            for (int w = 0; w < 8; ++w) s += sRed2[w][tid];
            out[row0 + tid] = s + ob2[0];
        }
    }
}

extern "C" void kernel_launch(void* const* d_in, const int* in_sizes, int n_in,
                              void* d_out, int out_size, void* d_ws, size_t ws_size,
                              hipStream_t stream)
{
    const float* x_p  = (const float*)d_in[0];
    const float* c_t  = (const float*)d_in[1];
    const float* c_a  = (const float*)d_in[2];
    const float* c_v  = (const float*)d_in[3];
    const float* memp = (const float*)d_in[4];

    u32* wsu = (u32*)d_ws;
    float* wsf = (float*)((char*)d_ws + (size_t)U32_TOTAL * 4);
    // total ws use: ~7.17 MB

    auto T = [&](const void* src, long off, int N, int K, int strideU, int rowOffK, int colOff) {
        long total = (long)N * K;
        int blocks = (int)((total + 255) / 256);
        hipLaunchKernelGGL(k_transpose, dim3(blocks), dim3(256), 0, stream,
                           (const float*)src, (unsigned short*)(wsu + off), N, K, strideU, rowOffK, colOff);
    };
    T(d_in[5],  OFF_TWI,  1024, 300, 1024, 0,   0);   // t_Wi
    T(d_in[6],  OFF_TWI,  1024, 256, 1024, 300, 0);   // t_Wh
    T(d_in[8],  OFF_AWI,  256,  74,  256,  0,   0);   // a_Wi
    T(d_in[9],  OFF_AWI,  256,  64,  256,  74,  0);   // a_Wh
    T(d_in[11], OFF_VWI,  256,  36,  256,  0,   0);   // v_Wi
    T(d_in[12], OFF_VWI,  256,  64,  256,  36,  0);   // v_Wh
    T(d_in[14], OFF_A1W1, 512,  768, 512,  0,   0);   // attn1_w1
    T(d_in[16], OFF_A1W2, 768,  512, 768,  0,   0);   // attn1_w2
    T(d_in[18], OFF_A2W1, 512,  768, 512,  0,   0);   // attn2_w1
    T(d_in[20], OFF_A2W2, 256,  512, 256,  0,   0);   // attn2_w2
    T(d_in[22], OFF_GW1,  512, 1024, 1024, 0,   0);   // g1_w1 -> cols 0-511
    T(d_in[26], OFF_GW1,  512, 1024, 1024, 0,   512); // g2_w1 -> cols 512-1023
    T(d_in[24], OFF_GW2,  256,  512, 512,  0,   0);   // g1_w2 -> cols 0-255
    T(d_in[28], OFF_GW2,  256,  512, 512,  0,   256); // g2_w2 -> cols 256-511
    T(d_in[30], OFF_OW1,  512,  640, 512,  0,   0);   // out_w1

    hipLaunchKernelGGL(k_packbias, dim3(6), dim3(256), 0, stream,
                       (const float*)d_in[23], (const float*)d_in[27],
                       (const float*)d_in[25], (const float*)d_in[29], wsf);

    hipLaunchKernelGGL(fused_rnn, dim3(128), dim3(512), 0, stream,
                       x_p, c_t, c_a, c_v, memp,
                       (const float*)d_in[7],  (const float*)d_in[10], (const float*)d_in[13],
                       (const float*)d_in[15], (const float*)d_in[17],
                       (const float*)d_in[19], (const float*)d_in[21],
                       (const float*)d_in[31], (const float*)d_in[32], (const float*)d_in[33],
                       wsu, wsf, (float*)d_out);
}